// Round 20
// baseline (80.077 us; speedup 1.0000x reference)
//
#include <hip/hip_runtime.h>
#include <hip/hip_bf16.h>

typedef __bf16 bf16x8 __attribute__((ext_vector_type(8)));
typedef __bf16 bf16x4 __attribute__((ext_vector_type(4)));
typedef float f32x4 __attribute__((ext_vector_type(4)));
typedef unsigned int u32x4 __attribute__((ext_vector_type(4)));

#define CIN 256
#define COUT 256
#define KDIM 2304  // 9*256

__device__ __forceinline__ void gload_lds16(const void* g, void* l) {
  __builtin_amdgcn_global_load_lds(
      (__attribute__((address_space(1))) unsigned int*)g,
      (__attribute__((address_space(3))) unsigned int*)l, 16, 0, 0);
}

// ---- kernel 1: all input prep, ONE launch
// blocks [0,288): w_dcn -> Ag bf16 [cout][tap*256+cin]   (8 elems/thread)
// blocks [288,324): w_off -> Ah (hi only) frag-coalesced (8 elems/thread)
// blocks [324,580): NCHW f32 -> NHWC bf16 via 8x8 register transpose
//   (was: 64 scalar 2B stores @512B stride per thread -> now 8 coalesced b128)
__global__ __launch_bounds__(256) void k_prep_all(const float* __restrict__ wdcn,
                                                  const float* __restrict__ woff,
                                                  const float* __restrict__ in,
                                                  __bf16* __restrict__ Ag,
                                                  __bf16* __restrict__ Ah,
                                                  __bf16* __restrict__ inT) {
  int bid = blockIdx.x, tid = threadIdx.x;
  if (bid < 288) {
    int t8 = bid * 256 + tid;  // 0..73727 ; elem base t = t8*8
    int cout = t8 / 288;
    int r8 = t8 - cout * 288;
    int tap = r8 >> 5;
    int cin0 = (r8 & 31) << 3;
    bf16x8 vv;
#pragma unroll
    for (int j = 0; j < 8; ++j)
      vv[j] = (__bf16)wdcn[(cout * 256 + cin0 + j) * 9 + tap];
    *(bf16x8*)&Ag[t8 << 3] = vv;
  } else if (bid < 324) {
    int t8 = (bid - 288) * 256 + tid;  // 0..9215 ; elem base t = t8*8
    int l = t8 & 63;
    int mh = (t8 >> 6) & 1;
    int s = t8 >> 7;  // 0..71
    int tap = s >> 3, cc = s & 7;
    int ki = tap / 3, kj = tap - ki * 3;
    int oc = mh * 16 + (l & 15);
    int cinb = cc * 32 + ((l >> 4) << 3);
    bf16x8 hv;
#pragma unroll
    for (int j = 0; j < 8; ++j) {
      float v = (oc < 27) ? woff[((oc * 256 + cinb + j) * 3 + ki) * 3 + kj] : 0.f;
      hv[j] = (__bf16)v;
    }
    *(bf16x8*)&Ah[t8 << 3] = hv;
  } else {
    int idx = bid - 324;  // 0..255
    int h = idx & 63, b = idx >> 6;
    int cg = tid >> 3;  // 0..31 cin-group of 8
    int wg = tid & 7;   // 0..7  w-group of 8
    const float* src = in + (((b << 8) + (cg << 3)) << 12) + (h << 6) + (wg << 3);
    float vals[8][8];
#pragma unroll
    for (int j = 0; j < 8; ++j) {
      f32x4 lo = *(const f32x4*)(src + (j << 12));
      f32x4 hi = *(const f32x4*)(src + (j << 12) + 4);
#pragma unroll
      for (int k = 0; k < 4; ++k) {
        vals[j][k] = lo[k];
        vals[j][4 + k] = hi[k];
      }
    }
#pragma unroll
    for (int k = 0; k < 8; ++k) {
      bf16x8 vv;
#pragma unroll
      for (int j = 0; j < 8; ++j) vv[j] = (__bf16)vals[j][k];
      *(bf16x8*)&inT[(((b << 12) + (h << 6) + (wg << 3) + k) << 8) + (cg << 3)] = vv;
    }
  }
}

// ---- kernel 2: offset conv as MFMA implicit GEMM (R19 verbatim: hi-only weights)
__global__ __launch_bounds__(256) void k_conv(const __bf16* __restrict__ inT,
                                              const __bf16* __restrict__ Ah,
                                              float* __restrict__ omp) {
  __shared__ __bf16 xh[3 * 4 * 66 * 8];  // 12.4 KB
  __shared__ __bf16 sW[9 * 1024];        // [tap][mh*512+l*8+j]: 18 KB
  int tid = threadIdx.x;
  int l = tid & 63, wn = tid >> 6;
  int ho = blockIdx.x, b = blockIdx.y, ct = blockIdx.z;

  f32x4 acc[2];
  acc[0] = (f32x4){0.f, 0.f, 0.f, 0.f};
  acc[1] = (f32x4){0.f, 0.f, 0.f, 0.f};

  for (int chunk = 0; chunk < 4; ++chunk) {
    int cin0 = ct * 128 + chunk * 32;
    int scc = ct * 4 + chunk;
    u32x4* sW4 = (u32x4*)sW;
#pragma unroll
    for (int i = 0; i < 5; ++i) {
      int s = i * 256 + tid;  // 0..1279; last partial masked
      if (s < 1152) {
        int tap = s >> 7, w = s & 127;
        const __bf16* src = Ah + (((tap * 8 + scc) * 2) << 9) + (w << 3);
        gload_lds16((const void*)src, (void*)&sW4[i * 256 + (tid & ~63)]);
      }
    }
    for (int i = tid; i < 792; i += 256) {  // (r,u,c): 3*4*66
      int c = i % 66;
      int t2 = i / 66;
      int u = t2 & 3, r = t2 >> 2;
      int h = ho - 1 + r, w = c - 1;
      bool ok = ((unsigned)h < 64u) & ((unsigned)w < 64u);
      bf16x8 hv = (bf16x8){};
      if (ok)
        hv = *(const bf16x8*)(inT + ((((b << 12) + (h << 6) + w)) << 8) + cin0 +
                              (u << 3));
      *(bf16x8*)&xh[((r * 4 + u) * 66 + c) << 3] = hv;
    }
    __syncthreads();  // drains vmcnt (sW DMA) + lgkm (xh writes)
#pragma unroll
    for (int tap = 0; tap < 9; ++tap) {
      int ki = tap / 3, kj = tap - ki * 3;
      bf16x8 ah0 = *(const bf16x8*)&sW[tap * 1024 + (l << 3)];
      bf16x8 ah1 = *(const bf16x8*)&sW[tap * 1024 + 512 + (l << 3)];
      int u = l >> 4;
      int sc = (wn << 4) + (l & 15) + kj;
      bf16x8 bh = *(const bf16x8*)&xh[((ki * 4 + u) * 66 + sc) << 3];
      acc[0] = __builtin_amdgcn_mfma_f32_16x16x32_bf16(ah0, bh, acc[0], 0, 0, 0);
      acc[1] = __builtin_amdgcn_mfma_f32_16x16x32_bf16(ah1, bh, acc[1], 0, 0, 0);
    }
    __syncthreads();
  }
  int n = (ho << 6) + (wn << 4) + (l & 15);
#pragma unroll
  for (int mh = 0; mh < 2; ++mh)
#pragma unroll
    for (int r = 0; r < 4; ++r) {
      int oc = mh * 16 + ((l >> 4) << 2) + r;
      if (oc < 27)
        omp[(((ct * 4 + b) * 27 + oc) << 12) + n] = acc[mh][r];
    }
}

// ---- kernel 3: fused deformable sampling + bf16 MFMA GEMM
// ROUND-15 VERBATIM (measured best: 62.0-62.5 us; R19's reg-staged A reverted)
__global__ __launch_bounds__(512, 4) void k_gemm(const __bf16* __restrict__ inT,
                                                 const float* __restrict__ omp,
                                                 const float* __restrict__ boff,
                                                 const __bf16* __restrict__ Ag,
                                                 const float* __restrict__ bdcn,
                                                 float* __restrict__ out) {
  __shared__ u32x4 sA[2048];  // [256 m][8 chunks] bf16, XOR-swizzled: 32 KB
  __shared__ u32x4 sB[256];   // [32 n][8 chunks]  bf16, XOR-swizzled:  4 KB
  int tid = threadIdx.x;
  int l = tid & 63;
  int w = tid >> 6;             // 0..7
  int wm = w & 3, wh = w >> 2;  // m-range wm*64; n-half wh*16
  int id = blockIdx.x;
  int x = id & 7, t = id >> 3;     // XCD map
  int b = x >> 1;
  int ntile = ((x & 1) << 6) + t;  // 0..127 (32-wide n tiles)
  int sn = tid >> 4;  // 0..31 n_local (16 lanes per n)
  int sc = tid & 15;  // 0..15 cin quad (4 cins each)
  int n_g = (ntile << 5) + sn;
  const __bf16* tb = inT + ((b << 12) << 8);  // batch base

  f32x4 acc[4];
#pragma unroll
  for (int i = 0; i < 4; ++i) acc[i] = (f32x4){0.f, 0.f, 0.f, 0.f};

  float w00 = 0.f, w01 = 0.f, w10 = 0.f, w11 = 0.f;
  int o00 = 0, o01 = 0, o10 = 0, o11 = 0;

  for (int step = 0; step < 36; ++step) {
    int tap = step >> 2;
    int cin0 = (step & 3) << 6;
    if ((step & 3) == 0) {
      int ki = tap / 3, kj = tap - ki * 3;
      float dy = omp[((b * 27 + 2 * tap) << 12) + n_g] +
                 omp[(((4 + b) * 27 + 2 * tap) << 12) + n_g] + boff[2 * tap];
      float dx = omp[((b * 27 + 2 * tap + 1) << 12) + n_g] +
                 omp[(((4 + b) * 27 + 2 * tap + 1) << 12) + n_g] + boff[2 * tap + 1];
      float mv = omp[((b * 27 + 18 + tap) << 12) + n_g] +
                 omp[(((4 + b) * 27 + 18 + tap) << 12) + n_g] + boff[18 + tap];
      float msk = 1.f / (1.f + __expf(-mv));
      float py = dy + (float)((n_g >> 6) - 1 + ki);
      float px = dx + (float)((n_g & 63) - 1 + kj);
      float y0f = floorf(py), x0f = floorf(px);
      float ly = py - y0f, lx = px - x0f;
      int y0 = (int)y0f, x0 = (int)x0f;
      int y1 = y0 + 1, x1 = x0 + 1;
      bool vy0 = (y0 >= 0) & (y0 < 64), vy1 = (y1 >= 0) & (y1 < 64);
      bool vx0 = (x0 >= 0) & (x0 < 64), vx1 = (x1 >= 0) & (x1 < 64);
      float hy = 1.f - ly, hx = 1.f - lx;
      w00 = (vy0 & vx0) ? hy * hx * msk : 0.f;
      w01 = (vy0 & vx1) ? hy * lx * msk : 0.f;
      w10 = (vy1 & vx0) ? ly * hx * msk : 0.f;
      w11 = (vy1 & vx1) ? ly * lx * msk : 0.f;
      int y0c = min(max(y0, 0), 63), y1c = min(max(y1, 0), 63);
      int x0c = min(max(x0, 0), 63), x1c = min(max(x1, 0), 63);
      o00 = (y0c << 6) + x0c;
      o01 = (y0c << 6) + x1c;
      o10 = (y1c << 6) + x0c;
      o11 = (y1c << 6) + x1c;
    }
    // wide gather: 4 corners x 4 cins (b64); 16 lanes cover a 128B run
    int cb0 = cin0 + (sc << 2);
    bf16x4 cA = *(const bf16x4*)(tb + (o00 << 8) + cb0);
    bf16x4 cB = *(const bf16x4*)(tb + (o01 << 8) + cb0);
    bf16x4 cC = *(const bf16x4*)(tb + (o10 << 8) + cb0);
    bf16x4 cD = *(const bf16x4*)(tb + (o11 << 8) + cb0);
    bf16x4 vv;
#pragma unroll
    for (int j = 0; j < 4; ++j) {
      vv[j] = (__bf16)(w00 * (float)cA[j] + w01 * (float)cB[j] +
                       w10 * (float)cC[j] + w11 * (float)cD[j]);
    }
    __syncthreads();  // barrier1: previous iteration's frag reads complete
    // stage A tile (proven swizzle, pre-swizzled source)
    int kk0 = (tap << 8) + cin0;
#pragma unroll
    for (int i = 0; i < 4; ++i) {
      int slot = i * 512 + tid;
      int m = slot >> 3, j = slot & 7;
      int csrc = j ^ (m & 7);
      const __bf16* src = Ag + m * KDIM + kk0 + (csrc << 3);
      gload_lds16((const void*)src, (void*)&sA[i * 512 + (tid & ~63)]);
    }
    // write B half-chunk (proven swizzled slot scheme)
    {
      unsigned long long* sB64 = (unsigned long long*)sB;
      int slot = (sn << 3) + ((sc >> 1) ^ (sn & 7));
      sB64[slot * 2 + (sc & 1)] = __builtin_bit_cast(unsigned long long, vv);
    }
    __syncthreads();  // barrier2: drains vmcnt (A stage) + lgkm (B writes)
#pragma unroll
    for (int kt = 0; kt < 2; ++kt) {
      bf16x8 af[4], bfr;
      int cc = (kt << 2) + (l >> 4);
#pragma unroll
      for (int mf = 0; mf < 4; ++mf) {
        int m = (wm << 6) + (mf << 4) + (l & 15);
        af[mf] = __builtin_bit_cast(bf16x8, sA[(m << 3) + (cc ^ (m & 7))]);
      }
      {
        int n = (wh << 4) + (l & 15);
        bfr = __builtin_bit_cast(bf16x8, sB[(n << 3) + (cc ^ (n & 7))]);
      }
#pragma unroll
      for (int mf = 0; mf < 4; ++mf)
        acc[mf] = __builtin_amdgcn_mfma_f32_16x16x32_bf16(af[mf], bfr, acc[mf],
                                                          0, 0, 0);
    }
  }
  // epilogue: C/D layout col=lane&15 (n), row=(lane>>4)*4+r (m)
#pragma unroll
  for (int mf = 0; mf < 4; ++mf)
#pragma unroll
    for (int r = 0; r < 4; ++r) {
      int m = (wm << 6) + (mf << 4) + ((l >> 4) << 2) + r;
      int n = (ntile << 5) + (wh << 4) + (l & 15);
      out[((b * COUT + m) << 12) + n] = acc[mf][r] + bdcn[m];
    }
}

extern "C" void kernel_launch(void* const* d_in, const int* in_sizes, int n_in,
                              void* d_out, int out_size, void* d_ws, size_t ws_size,
                              hipStream_t stream) {
  const float* in = (const float*)d_in[0];
  const float* woff = (const float*)d_in[1];
  const float* boff = (const float*)d_in[2];
  const float* wdcn = (const float*)d_in[3];
  const float* bdcn = (const float*)d_in[4];
  float* out = (float*)d_out;
  char* ws = (char*)d_ws;
  __bf16* Ag = (__bf16*)ws;                // 589824*2 = 1,179,648 B
  __bf16* Ah = (__bf16*)(ws + 1179648);    //  73728*2 =   147,456 B
  float* omp = (float*)(ws + 1474560);     // 2*4*27*4096*4 = 3,538,944 B
  __bf16* inT = (__bf16*)(ws + 5013504);   // 4*4096*256*2 = 8,388,608 B
  k_prep_all<<<580, 256, 0, stream>>>(wdcn, woff, in, Ag, Ah, inT);
  k_conv<<<dim3(64, 4, 2), 256, 0, stream>>>(inT, Ah, omp);
  k_gemm<<<512, 512, 0, stream>>>(inT, omp, boff, Ag, bdcn, out);
}

// Round 21
// 79.698 us; speedup vs baseline: 1.0047x; 1.0047x over previous
//
#include <hip/hip_runtime.h>
#include <hip/hip_bf16.h>

typedef __bf16 bf16x8 __attribute__((ext_vector_type(8)));
typedef __bf16 bf16x4 __attribute__((ext_vector_type(4)));
typedef float f32x4 __attribute__((ext_vector_type(4)));
typedef unsigned int u32x4 __attribute__((ext_vector_type(4)));

#define CIN 256
#define COUT 256
#define KDIM 2304  // 9*256

__device__ __forceinline__ void gload_lds16(const void* g, void* l) {
  __builtin_amdgcn_global_load_lds(
      (__attribute__((address_space(1))) unsigned int*)g,
      (__attribute__((address_space(3))) unsigned int*)l, 16, 0, 0);
}

// ---- kernel 1: all input prep, ONE launch (R19-verbatim: simple transpose)
// blocks [0,288): w_dcn -> Ag bf16 [cout][tap*256+cin]   (8 elems/thread)
// blocks [288,324): w_off -> Ah (hi only) frag-coalesced (8 elems/thread)
// blocks [324,580): NCHW f32 -> NHWC bf16 transpose (inT)
__global__ __launch_bounds__(256) void k_prep_all(const float* __restrict__ wdcn,
                                                  const float* __restrict__ woff,
                                                  const float* __restrict__ in,
                                                  __bf16* __restrict__ Ag,
                                                  __bf16* __restrict__ Ah,
                                                  __bf16* __restrict__ inT) {
  int bid = blockIdx.x, tid = threadIdx.x;
  if (bid < 288) {
    int t8 = bid * 256 + tid;  // 0..73727 ; elem base t = t8*8
    int cout = t8 / 288;
    int r8 = t8 - cout * 288;
    int tap = r8 >> 5;
    int cin0 = (r8 & 31) << 3;
    bf16x8 vv;
#pragma unroll
    for (int j = 0; j < 8; ++j)
      vv[j] = (__bf16)wdcn[(cout * 256 + cin0 + j) * 9 + tap];
    *(bf16x8*)&Ag[t8 << 3] = vv;
  } else if (bid < 324) {
    int t8 = (bid - 288) * 256 + tid;  // 0..9215 ; elem base t = t8*8
    int l = t8 & 63;
    int mh = (t8 >> 6) & 1;
    int s = t8 >> 7;  // 0..71
    int tap = s >> 3, cc = s & 7;
    int ki = tap / 3, kj = tap - ki * 3;
    int oc = mh * 16 + (l & 15);
    int cinb = cc * 32 + ((l >> 4) << 3);
    bf16x8 hv;
#pragma unroll
    for (int j = 0; j < 8; ++j) {
      float v = (oc < 27) ? woff[((oc * 256 + cinb + j) * 3 + ki) * 3 + kj] : 0.f;
      hv[j] = (__bf16)v;
    }
    *(bf16x8*)&Ah[t8 << 3] = hv;
  } else {
    int idx = bid - 324;  // 0..255
    int h = idx & 63, b = idx >> 6;
    int c = tid;
    const float* src = in + ((((b << 8) + c) << 6) + h) * 64;
    __bf16* dst = inT + (((b << 12) + (h << 6)) << 8) + c;
#pragma unroll
    for (int w4 = 0; w4 < 16; ++w4) {
      f32x4 v = *(const f32x4*)(src + (w4 << 2));
#pragma unroll
      for (int k = 0; k < 4; ++k) dst[(((w4 << 2) + k)) << 8] = (__bf16)v[k];
    }
  }
}

// ---- kernel 2: offset conv as MFMA implicit GEMM (R19 verbatim: hi-only weights)
__global__ __launch_bounds__(256) void k_conv(const __bf16* __restrict__ inT,
                                              const __bf16* __restrict__ Ah,
                                              float* __restrict__ omp) {
  __shared__ __bf16 xh[3 * 4 * 66 * 8];  // 12.4 KB
  __shared__ __bf16 sW[9 * 1024];        // [tap][mh*512+l*8+j]: 18 KB
  int tid = threadIdx.x;
  int l = tid & 63, wn = tid >> 6;
  int ho = blockIdx.x, b = blockIdx.y, ct = blockIdx.z;

  f32x4 acc[2];
  acc[0] = (f32x4){0.f, 0.f, 0.f, 0.f};
  acc[1] = (f32x4){0.f, 0.f, 0.f, 0.f};

  for (int chunk = 0; chunk < 4; ++chunk) {
    int cin0 = ct * 128 + chunk * 32;
    int scc = ct * 4 + chunk;
    u32x4* sW4 = (u32x4*)sW;
#pragma unroll
    for (int i = 0; i < 5; ++i) {
      int s = i * 256 + tid;  // 0..1279; last partial masked
      if (s < 1152) {
        int tap = s >> 7, w = s & 127;
        const __bf16* src = Ah + (((tap * 8 + scc) * 2) << 9) + (w << 3);
        gload_lds16((const void*)src, (void*)&sW4[i * 256 + (tid & ~63)]);
      }
    }
    for (int i = tid; i < 792; i += 256) {  // (r,u,c): 3*4*66
      int c = i % 66;
      int t2 = i / 66;
      int u = t2 & 3, r = t2 >> 2;
      int h = ho - 1 + r, w = c - 1;
      bool ok = ((unsigned)h < 64u) & ((unsigned)w < 64u);
      bf16x8 hv = (bf16x8){};
      if (ok)
        hv = *(const bf16x8*)(inT + ((((b << 12) + (h << 6) + w)) << 8) + cin0 +
                              (u << 3));
      *(bf16x8*)&xh[((r * 4 + u) * 66 + c) << 3] = hv;
    }
    __syncthreads();  // drains vmcnt (sW DMA) + lgkm (xh writes)
#pragma unroll
    for (int tap = 0; tap < 9; ++tap) {
      int ki = tap / 3, kj = tap - ki * 3;
      bf16x8 ah0 = *(const bf16x8*)&sW[tap * 1024 + (l << 3)];
      bf16x8 ah1 = *(const bf16x8*)&sW[tap * 1024 + 512 + (l << 3)];
      int u = l >> 4;
      int sc = (wn << 4) + (l & 15) + kj;
      bf16x8 bh = *(const bf16x8*)&xh[((ki * 4 + u) * 66 + sc) << 3];
      acc[0] = __builtin_amdgcn_mfma_f32_16x16x32_bf16(ah0, bh, acc[0], 0, 0, 0);
      acc[1] = __builtin_amdgcn_mfma_f32_16x16x32_bf16(ah1, bh, acc[1], 0, 0, 0);
    }
    __syncthreads();
  }
  int n = (ho << 6) + (wn << 4) + (l & 15);
#pragma unroll
  for (int mh = 0; mh < 2; ++mh)
#pragma unroll
    for (int r = 0; r < 4; ++r) {
      int oc = mh * 16 + ((l >> 4) << 2) + r;
      if (oc < 27)
        omp[(((ct * 4 + b) * 27 + oc) << 12) + n] = acc[mh][r];
    }
}

// ---- kernel 3: fused deformable sampling + bf16 MFMA GEMM
// ROUND-15 VERBATIM (measured best: 62.0-62.5 us)
__global__ __launch_bounds__(512, 4) void k_gemm(const __bf16* __restrict__ inT,
                                                 const float* __restrict__ omp,
                                                 const float* __restrict__ boff,
                                                 const __bf16* __restrict__ Ag,
                                                 const float* __restrict__ bdcn,
                                                 float* __restrict__ out) {
  __shared__ u32x4 sA[2048];  // [256 m][8 chunks] bf16, XOR-swizzled: 32 KB
  __shared__ u32x4 sB[256];   // [32 n][8 chunks]  bf16, XOR-swizzled:  4 KB
  int tid = threadIdx.x;
  int l = tid & 63;
  int w = tid >> 6;             // 0..7
  int wm = w & 3, wh = w >> 2;  // m-range wm*64; n-half wh*16
  int id = blockIdx.x;
  int x = id & 7, t = id >> 3;     // XCD map
  int b = x >> 1;
  int ntile = ((x & 1) << 6) + t;  // 0..127 (32-wide n tiles)
  int sn = tid >> 4;  // 0..31 n_local (16 lanes per n)
  int sc = tid & 15;  // 0..15 cin quad (4 cins each)
  int n_g = (ntile << 5) + sn;
  const __bf16* tb = inT + ((b << 12) << 8);  // batch base

  f32x4 acc[4];
#pragma unroll
  for (int i = 0; i < 4; ++i) acc[i] = (f32x4){0.f, 0.f, 0.f, 0.f};

  float w00 = 0.f, w01 = 0.f, w10 = 0.f, w11 = 0.f;
  int o00 = 0, o01 = 0, o10 = 0, o11 = 0;

  for (int step = 0; step < 36; ++step) {
    int tap = step >> 2;
    int cin0 = (step & 3) << 6;
    if ((step & 3) == 0) {
      int ki = tap / 3, kj = tap - ki * 3;
      float dy = omp[((b * 27 + 2 * tap) << 12) + n_g] +
                 omp[(((4 + b) * 27 + 2 * tap) << 12) + n_g] + boff[2 * tap];
      float dx = omp[((b * 27 + 2 * tap + 1) << 12) + n_g] +
                 omp[(((4 + b) * 27 + 2 * tap + 1) << 12) + n_g] + boff[2 * tap + 1];
      float mv = omp[((b * 27 + 18 + tap) << 12) + n_g] +
                 omp[(((4 + b) * 27 + 18 + tap) << 12) + n_g] + boff[18 + tap];
      float msk = 1.f / (1.f + __expf(-mv));
      float py = dy + (float)((n_g >> 6) - 1 + ki);
      float px = dx + (float)((n_g & 63) - 1 + kj);
      float y0f = floorf(py), x0f = floorf(px);
      float ly = py - y0f, lx = px - x0f;
      int y0 = (int)y0f, x0 = (int)x0f;
      int y1 = y0 + 1, x1 = x0 + 1;
      bool vy0 = (y0 >= 0) & (y0 < 64), vy1 = (y1 >= 0) & (y1 < 64);
      bool vx0 = (x0 >= 0) & (x0 < 64), vx1 = (x1 >= 0) & (x1 < 64);
      float hy = 1.f - ly, hx = 1.f - lx;
      w00 = (vy0 & vx0) ? hy * hx * msk : 0.f;
      w01 = (vy0 & vx1) ? hy * lx * msk : 0.f;
      w10 = (vy1 & vx0) ? ly * hx * msk : 0.f;
      w11 = (vy1 & vx1) ? ly * lx * msk : 0.f;
      int y0c = min(max(y0, 0), 63), y1c = min(max(y1, 0), 63);
      int x0c = min(max(x0, 0), 63), x1c = min(max(x1, 0), 63);
      o00 = (y0c << 6) + x0c;
      o01 = (y0c << 6) + x1c;
      o10 = (y1c << 6) + x0c;
      o11 = (y1c << 6) + x1c;
    }
    // wide gather: 4 corners x 4 cins (b64); 16 lanes cover a 128B run
    int cb0 = cin0 + (sc << 2);
    bf16x4 cA = *(const bf16x4*)(tb + (o00 << 8) + cb0);
    bf16x4 cB = *(const bf16x4*)(tb + (o01 << 8) + cb0);
    bf16x4 cC = *(const bf16x4*)(tb + (o10 << 8) + cb0);
    bf16x4 cD = *(const bf16x4*)(tb + (o11 << 8) + cb0);
    bf16x4 vv;
#pragma unroll
    for (int j = 0; j < 4; ++j) {
      vv[j] = (__bf16)(w00 * (float)cA[j] + w01 * (float)cB[j] +
                       w10 * (float)cC[j] + w11 * (float)cD[j]);
    }
    __syncthreads();  // barrier1: previous iteration's frag reads complete
    // stage A tile (proven swizzle, pre-swizzled source)
    int kk0 = (tap << 8) + cin0;
#pragma unroll
    for (int i = 0; i < 4; ++i) {
      int slot = i * 512 + tid;
      int m = slot >> 3, j = slot & 7;
      int csrc = j ^ (m & 7);
      const __bf16* src = Ag + m * KDIM + kk0 + (csrc << 3);
      gload_lds16((const void*)src, (void*)&sA[i * 512 + (tid & ~63)]);
    }
    // write B half-chunk (proven swizzled slot scheme)
    {
      unsigned long long* sB64 = (unsigned long long*)sB;
      int slot = (sn << 3) + ((sc >> 1) ^ (sn & 7));
      sB64[slot * 2 + (sc & 1)] = __builtin_bit_cast(unsigned long long, vv);
    }
    __syncthreads();  // barrier2: drains vmcnt (A stage) + lgkm (B writes)
#pragma unroll
    for (int kt = 0; kt < 2; ++kt) {
      bf16x8 af[4], bfr;
      int cc = (kt << 2) + (l >> 4);
#pragma unroll
      for (int mf = 0; mf < 4; ++mf) {
        int m = (wm << 6) + (mf << 4) + (l & 15);
        af[mf] = __builtin_bit_cast(bf16x8, sA[(m << 3) + (cc ^ (m & 7))]);
      }
      {
        int n = (wh << 4) + (l & 15);
        bfr = __builtin_bit_cast(bf16x8, sB[(n << 3) + (cc ^ (n & 7))]);
      }
#pragma unroll
      for (int mf = 0; mf < 4; ++mf)
        acc[mf] = __builtin_amdgcn_mfma_f32_16x16x32_bf16(af[mf], bfr, acc[mf],
                                                          0, 0, 0);
    }
  }
  // epilogue: C/D layout col=lane&15 (n), row=(lane>>4)*4+r (m)
#pragma unroll
  for (int mf = 0; mf < 4; ++mf)
#pragma unroll
    for (int r = 0; r < 4; ++r) {
      int m = (wm << 6) + (mf << 4) + ((l >> 4) << 2) + r;
      int n = (ntile << 5) + (wh << 4) + (l & 15);
      out[((b * COUT + m) << 12) + n] = acc[mf][r] + bdcn[m];
    }
}

extern "C" void kernel_launch(void* const* d_in, const int* in_sizes, int n_in,
                              void* d_out, int out_size, void* d_ws, size_t ws_size,
                              hipStream_t stream) {
  const float* in = (const float*)d_in[0];
  const float* woff = (const float*)d_in[1];
  const float* boff = (const float*)d_in[2];
  const float* wdcn = (const float*)d_in[3];
  const float* bdcn = (const float*)d_in[4];
  float* out = (float*)d_out;
  char* ws = (char*)d_ws;
  __bf16* Ag = (__bf16*)ws;                // 589824*2 = 1,179,648 B
  __bf16* Ah = (__bf16*)(ws + 1179648);    //  73728*2 =   147,456 B
  float* omp = (float*)(ws + 1474560);     // 2*4*27*4096*4 = 3,538,944 B
  __bf16* inT = (__bf16*)(ws + 5013504);   // 4*4096*256*2 = 8,388,608 B
  k_prep_all<<<580, 256, 0, stream>>>(wdcn, woff, in, Ag, Ah, inT);
  k_conv<<<dim3(64, 4, 2), 256, 0, stream>>>(inT, Ah, omp);
  k_gemm<<<512, 512, 0, stream>>>(inT, omp, boff, Ag, bdcn, out);
}

// Round 22
// 77.387 us; speedup vs baseline: 1.0348x; 1.0299x over previous
//
#include <hip/hip_runtime.h>
#include <hip/hip_bf16.h>

typedef __bf16 bf16x8 __attribute__((ext_vector_type(8)));
typedef __bf16 bf16x4 __attribute__((ext_vector_type(4)));
typedef float f32x4 __attribute__((ext_vector_type(4)));
typedef unsigned int u32x4 __attribute__((ext_vector_type(4)));

#define CIN 256
#define COUT 256
#define KDIM 2304  // 9*256

__device__ __forceinline__ void gload_lds16(const void* g, void* l) {
  __builtin_amdgcn_global_load_lds(
      (__attribute__((address_space(1))) unsigned int*)g,
      (__attribute__((address_space(3))) unsigned int*)l, 16, 0, 0);
}

// ---- kernel 1: all input prep, ONE launch (R21 verbatim)
__global__ __launch_bounds__(256) void k_prep_all(const float* __restrict__ wdcn,
                                                  const float* __restrict__ woff,
                                                  const float* __restrict__ in,
                                                  __bf16* __restrict__ Ag,
                                                  __bf16* __restrict__ Ah,
                                                  __bf16* __restrict__ inT) {
  int bid = blockIdx.x, tid = threadIdx.x;
  if (bid < 288) {
    int t8 = bid * 256 + tid;  // 0..73727 ; elem base t = t8*8
    int cout = t8 / 288;
    int r8 = t8 - cout * 288;
    int tap = r8 >> 5;
    int cin0 = (r8 & 31) << 3;
    bf16x8 vv;
#pragma unroll
    for (int j = 0; j < 8; ++j)
      vv[j] = (__bf16)wdcn[(cout * 256 + cin0 + j) * 9 + tap];
    *(bf16x8*)&Ag[t8 << 3] = vv;
  } else if (bid < 324) {
    int t8 = (bid - 288) * 256 + tid;  // 0..9215 ; elem base t = t8*8
    int l = t8 & 63;
    int mh = (t8 >> 6) & 1;
    int s = t8 >> 7;  // 0..71
    int tap = s >> 3, cc = s & 7;
    int ki = tap / 3, kj = tap - ki * 3;
    int oc = mh * 16 + (l & 15);
    int cinb = cc * 32 + ((l >> 4) << 3);
    bf16x8 hv;
#pragma unroll
    for (int j = 0; j < 8; ++j) {
      float v = (oc < 27) ? woff[((oc * 256 + cinb + j) * 3 + ki) * 3 + kj] : 0.f;
      hv[j] = (__bf16)v;
    }
    *(bf16x8*)&Ah[t8 << 3] = hv;
  } else {
    int idx = bid - 324;  // 0..255
    int h = idx & 63, b = idx >> 6;
    int c = tid;
    const float* src = in + ((((b << 8) + c) << 6) + h) * 64;
    __bf16* dst = inT + (((b << 12) + (h << 6)) << 8) + c;
#pragma unroll
    for (int w4 = 0; w4 < 16; ++w4) {
      f32x4 v = *(const f32x4*)(src + (w4 << 2));
#pragma unroll
      for (int k = 0; k < 4; ++k) dst[(((w4 << 2) + k)) << 8] = (__bf16)v[k];
    }
  }
}

// ---- kernel 2: offset conv as MFMA implicit GEMM (R21 verbatim)
__global__ __launch_bounds__(256) void k_conv(const __bf16* __restrict__ inT,
                                              const __bf16* __restrict__ Ah,
                                              float* __restrict__ omp) {
  __shared__ __bf16 xh[3 * 4 * 66 * 8];  // 12.4 KB
  __shared__ __bf16 sW[9 * 1024];        // [tap][mh*512+l*8+j]: 18 KB
  int tid = threadIdx.x;
  int l = tid & 63, wn = tid >> 6;
  int ho = blockIdx.x, b = blockIdx.y, ct = blockIdx.z;

  f32x4 acc[2];
  acc[0] = (f32x4){0.f, 0.f, 0.f, 0.f};
  acc[1] = (f32x4){0.f, 0.f, 0.f, 0.f};

  for (int chunk = 0; chunk < 4; ++chunk) {
    int cin0 = ct * 128 + chunk * 32;
    int scc = ct * 4 + chunk;
    u32x4* sW4 = (u32x4*)sW;
#pragma unroll
    for (int i = 0; i < 5; ++i) {
      int s = i * 256 + tid;  // 0..1279; last partial masked
      if (s < 1152) {
        int tap = s >> 7, w = s & 127;
        const __bf16* src = Ah + (((tap * 8 + scc) * 2) << 9) + (w << 3);
        gload_lds16((const void*)src, (void*)&sW4[i * 256 + (tid & ~63)]);
      }
    }
    for (int i = tid; i < 792; i += 256) {  // (r,u,c): 3*4*66
      int c = i % 66;
      int t2 = i / 66;
      int u = t2 & 3, r = t2 >> 2;
      int h = ho - 1 + r, w = c - 1;
      bool ok = ((unsigned)h < 64u) & ((unsigned)w < 64u);
      bf16x8 hv = (bf16x8){};
      if (ok)
        hv = *(const bf16x8*)(inT + ((((b << 12) + (h << 6) + w)) << 8) + cin0 +
                              (u << 3));
      *(bf16x8*)&xh[((r * 4 + u) * 66 + c) << 3] = hv;
    }
    __syncthreads();  // drains vmcnt (sW DMA) + lgkm (xh writes)
#pragma unroll
    for (int tap = 0; tap < 9; ++tap) {
      int ki = tap / 3, kj = tap - ki * 3;
      bf16x8 ah0 = *(const bf16x8*)&sW[tap * 1024 + (l << 3)];
      bf16x8 ah1 = *(const bf16x8*)&sW[tap * 1024 + 512 + (l << 3)];
      int u = l >> 4;
      int sc = (wn << 4) + (l & 15) + kj;
      bf16x8 bh = *(const bf16x8*)&xh[((ki * 4 + u) * 66 + sc) << 3];
      acc[0] = __builtin_amdgcn_mfma_f32_16x16x32_bf16(ah0, bh, acc[0], 0, 0, 0);
      acc[1] = __builtin_amdgcn_mfma_f32_16x16x32_bf16(ah1, bh, acc[1], 0, 0, 0);
    }
    __syncthreads();
  }
  int n = (ho << 6) + (wn << 4) + (l & 15);
#pragma unroll
  for (int mh = 0; mh < 2; ++mh)
#pragma unroll
    for (int r = 0; r < 4; ++r) {
      int oc = mh * 16 + ((l >> 4) << 2) + r;
      if (oc < 27)
        omp[(((ct * 4 + b) * 27 + oc) << 12) + n] = acc[mh][r];
    }
}

// ---- kernel 3: fused deformable sampling + bf16 MFMA GEMM
// Round-22: counted-vmcnt pipeline BY ISSUE ORDER. Per iter: combine(s) ->
// sb_write sB[s&1] -> issue gathers(s+1) -> lgkm-barrier -> MFMA(s) ->
// lgkm-barrier -> issue DMA-A(s+2) into the buffer MFMA(s) just freed.
// combine(s)'s compiler wait (gathers(s)) is vmcnt(4): retires DMA-A(s)
// (older), leaves DMA-A(s+1) in flight across BOTH barriers -> no barrier
// ever drains vmem. Safety: wave passes bar1(s) => all waves ran combine(s)
// => all DMA-A(s) slices retired; DMA-A(s+2) targets sA[s&1] only after
// bar2(s) (all MFMA(s) reads done); sB ping-pong has 2 barriers separation.
__global__ __launch_bounds__(512, 4) void k_gemm(const __bf16* __restrict__ inT,
                                                 const float* __restrict__ omp,
                                                 const float* __restrict__ boff,
                                                 const __bf16* __restrict__ Ag,
                                                 const float* __restrict__ bdcn,
                                                 float* __restrict__ out) {
  __shared__ u32x4 sA[2][2048];  // 2 x [256 m][8 chunks] bf16, swizzled: 64 KB
  __shared__ u32x4 sB[2][256];   // 2 x [32 n][8 chunks]  bf16, swizzled:  8 KB
  int tid = threadIdx.x;
  int l = tid & 63;
  int w = tid >> 6;             // 0..7
  int wm = w & 3, wh = w >> 2;  // m-range wm*64; n-half wh*16
  int id = blockIdx.x;
  int x = id & 7, t = id >> 3;     // XCD map
  int b = x >> 1;
  int ntile = ((x & 1) << 6) + t;  // 0..127 (32-wide n tiles)
  int sn = tid >> 4;  // 0..31 n_local (16 lanes per n)
  int sc = tid & 15;  // 0..15 cin quad (4 cins each)
  int n_g = (ntile << 5) + sn;
  const __bf16* tb = inT + ((b << 12) << 8);  // batch base

  f32x4 acc[4];
#pragma unroll
  for (int i = 0; i < 4; ++i) acc[i] = (f32x4){0.f, 0.f, 0.f, 0.f};

  float w00 = 0.f, w01 = 0.f, w10 = 0.f, w11 = 0.f;
  int o00 = 0, o01 = 0, o10 = 0, o11 = 0;
  bf16x4 cA, cB, cC, cD;

  auto do_corners = [&](int tap) {
    int ki = tap / 3, kj = tap - ki * 3;
    float dy = omp[((b * 27 + 2 * tap) << 12) + n_g] +
               omp[(((4 + b) * 27 + 2 * tap) << 12) + n_g] + boff[2 * tap];
    float dx = omp[((b * 27 + 2 * tap + 1) << 12) + n_g] +
               omp[(((4 + b) * 27 + 2 * tap + 1) << 12) + n_g] + boff[2 * tap + 1];
    float mv = omp[((b * 27 + 18 + tap) << 12) + n_g] +
               omp[(((4 + b) * 27 + 18 + tap) << 12) + n_g] + boff[18 + tap];
    float msk = 1.f / (1.f + __expf(-mv));
    float py = dy + (float)((n_g >> 6) - 1 + ki);
    float px = dx + (float)((n_g & 63) - 1 + kj);
    float y0f = floorf(py), x0f = floorf(px);
    float ly = py - y0f, lx = px - x0f;
    int y0 = (int)y0f, x0 = (int)x0f;
    int y1 = y0 + 1, x1 = x0 + 1;
    bool vy0 = (y0 >= 0) & (y0 < 64), vy1 = (y1 >= 0) & (y1 < 64);
    bool vx0 = (x0 >= 0) & (x0 < 64), vx1 = (x1 >= 0) & (x1 < 64);
    float hy = 1.f - ly, hx = 1.f - lx;
    w00 = (vy0 & vx0) ? hy * hx * msk : 0.f;
    w01 = (vy0 & vx1) ? hy * lx * msk : 0.f;
    w10 = (vy1 & vx0) ? ly * hx * msk : 0.f;
    w11 = (vy1 & vx1) ? ly * lx * msk : 0.f;
    int y0c = min(max(y0, 0), 63), y1c = min(max(y1, 0), 63);
    int x0c = min(max(x0, 0), 63), x1c = min(max(x1, 0), 63);
    o00 = (y0c << 6) + x0c;
    o01 = (y0c << 6) + x1c;
    o10 = (y1c << 6) + x0c;
    o11 = (y1c << 6) + x1c;
  };
  auto do_gather = [&](int s1) {
    int cb0 = ((s1 & 3) << 6) + (sc << 2);
    cA = *(const bf16x4*)(tb + (o00 << 8) + cb0);
    cB = *(const bf16x4*)(tb + (o01 << 8) + cb0);
    cC = *(const bf16x4*)(tb + (o10 << 8) + cb0);
    cD = *(const bf16x4*)(tb + (o11 << 8) + cb0);
  };
  auto dma_A = [&](int s1, int buf) {
    int kk0 = s1 << 6;  // tap*256 + cin0 == step*64
#pragma unroll
    for (int i = 0; i < 4; ++i) {
      int slot = i * 512 + tid;
      int m = slot >> 3, j = slot & 7;
      int csrc = j ^ (m & 7);
      const __bf16* src = Ag + m * KDIM + kk0 + (csrc << 3);
      gload_lds16((const void*)src, (void*)&sA[buf][i * 512 + (tid & ~63)]);
    }
  };
  auto barrier_lgkm = [&]() {
    asm volatile("s_waitcnt lgkmcnt(0)" ::: "memory");
    __builtin_amdgcn_s_barrier();
  };

  // prologue — issue order matters: DMA-A(0) OLDEST, then gathers(0), then
  // DMA-A(1). combine(0)'s wait on gathers(0) retires DMA-A(0), leaves DMA-A(1).
  do_corners(0);
  dma_A(0, 0);
  do_gather(0);
  dma_A(1, 1);

  for (int s = 0; s < 36; ++s) {
    // combine(s): compiler-counted vmcnt wait (retires gathers(s)+DMA-A(s))
    bf16x4 vv;
#pragma unroll
    for (int j = 0; j < 4; ++j) {
      vv[j] = (__bf16)(w00 * (float)cA[j] + w01 * (float)cB[j] +
                       w10 * (float)cC[j] + w11 * (float)cD[j]);
    }
    // write B chunk into sB[s&1] (proven swizzled slot scheme)
    {
      unsigned long long* sB64 = (unsigned long long*)&sB[s & 1][0];
      int slot = (sn << 3) + ((sc >> 1) ^ (sn & 7));
      sB64[slot * 2 + (sc & 1)] = __builtin_bit_cast(unsigned long long, vv);
    }
    // issue next gathers BEFORE any DMA this iter (keeps waits counted)
    if (s < 35) {
      int s1 = s + 1;
      if ((s1 & 3) == 0) do_corners(s1 >> 2);
      do_gather(s1);
    }
    barrier_lgkm();  // bar1: sB[s&1] visible; all waves' DMA-A(s) retired
    // MFMA(s) on sA[s&1], sB[s&1]
    int pb = s & 1;
#pragma unroll
    for (int kt = 0; kt < 2; ++kt) {
      bf16x8 af[4], bfr;
      int cc = (kt << 2) + (l >> 4);
#pragma unroll
      for (int mf = 0; mf < 4; ++mf) {
        int m = (wm << 6) + (mf << 4) + (l & 15);
        af[mf] = __builtin_bit_cast(bf16x8, sA[pb][(m << 3) + (cc ^ (m & 7))]);
      }
      {
        int n = (wh << 4) + (l & 15);
        bfr = __builtin_bit_cast(bf16x8, sB[pb][(n << 3) + (cc ^ (n & 7))]);
      }
#pragma unroll
      for (int mf = 0; mf < 4; ++mf)
        acc[mf] = __builtin_amdgcn_mfma_f32_16x16x32_bf16(af[mf], bfr, acc[mf],
                                                          0, 0, 0);
    }
    barrier_lgkm();  // bar2: all MFMA(s) LDS reads complete -> buffer free
    if (s < 34) dma_A(s + 2, s & 1);  // refill freed buffer; stays in flight
  }

  // epilogue: C/D layout col=lane&15 (n), row=(lane>>4)*4+r (m)
#pragma unroll
  for (int mf = 0; mf < 4; ++mf)
#pragma unroll
    for (int r = 0; r < 4; ++r) {
      int m = (wm << 6) + (mf << 4) + ((l >> 4) << 2) + r;
      int n = (ntile << 5) + (wh << 4) + (l & 15);
      out[((b * COUT + m) << 12) + n] = acc[mf][r] + bdcn[m];
    }
}

extern "C" void kernel_launch(void* const* d_in, const int* in_sizes, int n_in,
                              void* d_out, int out_size, void* d_ws, size_t ws_size,
                              hipStream_t stream) {
  const float* in = (const float*)d_in[0];
  const float* woff = (const float*)d_in[1];
  const float* boff = (const float*)d_in[2];
  const float* wdcn = (const float*)d_in[3];
  const float* bdcn = (const float*)d_in[4];
  float* out = (float*)d_out;
  char* ws = (char*)d_ws;
  __bf16* Ag = (__bf16*)ws;                // 589824*2 = 1,179,648 B
  __bf16* Ah = (__bf16*)(ws + 1179648);    //  73728*2 =   147,456 B
  float* omp = (float*)(ws + 1474560);     // 2*4*27*4096*4 = 3,538,944 B
  __bf16* inT = (__bf16*)(ws + 5013504);   // 4*4096*256*2 = 8,388,608 B
  k_prep_all<<<580, 256, 0, stream>>>(wdcn, woff, in, Ag, Ah, inT);
  k_conv<<<dim3(64, 4, 2), 256, 0, stream>>>(inT, Ah, omp);
  k_gemm<<<512, 512, 0, stream>>>(inT, omp, boff, Ag, bdcn, out);
}